// Round 12
// baseline (108.302 us; speedup 1.0000x reference)
//
#include <hip/hip_runtime.h>

#define HH 512        // sinogram height (H_IN)
#define WW 360        // angles (W_IN)
#define NB 4          // batch
#define DD 512        // output D

#define NCHUNK 6
#define ANG_PER 60                          // 360/6

#define FSTRIDE 768                         // float4 rows per angle: 128 zero | 512 data | 128 zero
#define FOFFS   128                         // data row offset within stride
#define NR      128                         // staged window rows (span <= 69 + slack)

// ws layout in floats
#define OFF_TAB  0                          // float2 tab[360] -> 1024 floats
#define OFF_FILT 1024                       // filt_pad [361][768] float4
#define OFF_PART (OFF_FILT + (WW+1)*FSTRIDE*4)  // parts [6][512*512] float4
#define PIX (DD*DD)

#define GLOAD_LDS16(gp, lp)                                                   \
    __builtin_amdgcn_global_load_lds(                                         \
        (const __attribute__((address_space(1))) void*)(gp),                  \
        (__attribute__((address_space(3))) void*)(lp), 16, 0, 0)

// ---------------- K1: fused transpose + circular ramp filter ----------------
// r2[n][i] = radon[n][(i+257)&511][wA]  (strided loads, radon is L2-resident)
// filt_pad[wA][FOFFS+y] = float4{ v_n(y) }, rows [0,128) and [640,768) zeroed.
__global__ __launch_bounds__(256) void k_filter(const float* __restrict__ radon,
                                                const float* __restrict__ hG,
                                                float* __restrict__ ws) {
    __shared__ float r2[NB][1024];          // duplicated circular span
    int wA  = blockIdx.x;
    int tid = threadIdx.x;

    if (tid == 0) {                          // angle table (double trig, validated)
        double th = (3.14159265358979323846 / 180.0) * (0.5 * (double)wA);
        double c = cos(th), s = sin(th);
        float2 ab;
        ab.x = (float)(c * (255.5 / 256.0));
        ab.y = (float)(-s * (255.5 / 256.0));
        ((float2*)(ws + OFF_TAB))[wA] = ab;
    }
    {   // zero pad rows of this angle's filt slot
        float4* fp = (float4*)(ws + OFF_FILT) + (size_t)wA * FSTRIDE;
        float4 z = make_float4(0.f, 0.f, 0.f, 0.f);
        if (tid < 128) { fp[tid] = z; fp[640 + tid] = z; }
    }

    // fused transpose: 16 strided loads per thread
    for (int t = tid; t < NB * 1024; t += 256) {
        int n = t >> 10, i = t & 1023;
        int h = (i + 257) & 511;
        r2[n][i] = radon[((size_t)(n * HH + h)) * WW + wA];
    }
    __syncthreads();

    int n = tid >> 6, lane = tid & 63, y0 = lane << 3;   // 8 consecutive y per thread
    float acc[8] = {0, 0, 0, 0, 0, 0, 0, 0};
    const float* rr = &r2[n][y0];
    float4 Wr0 = *(const float4*)(rr + 0);
    float4 Wr1 = *(const float4*)(rr + 4);
    float4 Wr2 = *(const float4*)(rr + 8);
    float4 Wr3 = *(const float4*)(rr + 12);

    for (int d = 0; d < 512; d += 8) {
        float hg[8];
#pragma unroll
        for (int q = 0; q < 8; ++q) hg[q] = hG[d + q];   // uniform -> s_load
        float wf[16] = {Wr0.x, Wr0.y, Wr0.z, Wr0.w, Wr1.x, Wr1.y, Wr1.z, Wr1.w,
                        Wr2.x, Wr2.y, Wr2.z, Wr2.w, Wr3.x, Wr3.y, Wr3.z, Wr3.w};
#pragma unroll
        for (int du = 0; du < 8; ++du)
#pragma unroll
            for (int u = 0; u < 8; ++u)
                acc[u] = fmaf(wf[du + u], hg[du], acc[u]);
        if (d < 504) {
            Wr0 = Wr2; Wr1 = Wr3;
            Wr2 = *(const float4*)(rr + d + 16);
            Wr3 = *(const float4*)(rr + d + 20);
        }
    }
    float* filt = ws + OFF_FILT;
#pragma unroll
    for (int u = 0; u < 8; ++u)
        filt[((size_t)wA * FSTRIDE + FOFFS + y0 + u) * 4 + n] = acc[u];
}

// ---------------- K2: backprojection, depth-3 counted-vmcnt pipeline ----------------
// NCHUNK=6, 16-row i-tiles: grid (8,32,6) = 1536 blocks = 6 blocks/CU.
// 4 rotating 2KB window buffers; DMA(k) issued 3 iterations ahead;
// s_waitcnt vmcnt(2) + raw s_barrier per angle (never drains to 0 in-loop).
__global__ __launch_bounds__(256, 6) void k_backproj(const float* __restrict__ ws,
                                                     float* __restrict__ parts) {
    __shared__ float4 buf[4][NR];           // 8 KB rotating windows
    __shared__ float2 tl[ANG_PER];          // this chunk's angle table
    const int tid   = threadIdx.x;
    const int lane  = tid & 63;
    const int ithr  = tid >> 6;             // 0..3
    const int j     = blockIdx.x * 64 + lane;
    const int i0    = blockIdx.y * 16 + ithr;   // i = i0 + 4u, u<4
    const int chunk = blockIdx.z;
    const int wbeg  = chunk * ANG_PER;

    const float2* tab = (const float2*)(ws + OFF_TAB);
    const float4* fd  = (const float4*)(ws + OFF_FILT);

    if (tid < ANG_PER) tl[tid] = tab[wbeg + tid];
    __syncthreads();                        // tab resident; vmcnt drained (no DMAs yet)

    float acc[4][4];
#pragma unroll
    for (int u = 0; u < 4; ++u)
#pragma unroll
        for (int n = 0; n < 4; ++n) acc[u][n] = 0.f;

    float jf = (float)(j - 256);
    float ifl[4];
#pragma unroll
    for (int u = 0; u < 4; ++u) ifl[u] = (float)(i0 + 4 * u - 256);

    // tile corner coordinates (uniform per block); fp32 fma monotone per arg
    const float jlo = (float)((int)blockIdx.x * 64 - 256);
    const float jhi = (float)((int)blockIdx.x * 64 + 63 - 256);
    const float ilo = (float)((int)blockIdx.y * 16 - 256);
    const float ihi = (float)((int)blockIdx.y * 16 + 15 - 256);

#define CALC_BASE(ab, dst)                                                    \
    {                                                                         \
        float t_ = fminf(fmaf((ab).x, jlo, 255.5f), fmaf((ab).x, jhi, 255.5f)); \
        float pm_ = fminf(fmaf((ab).y, ilo, t_), fmaf((ab).y, ihi, t_));      \
        (dst) = floorf(pm_) - 2.0f;                                           \
    }

    float2 abA = tl[0], abB = tl[1], abC = tl[2], abD;
    float bA, bB, bC, bD;
    CALC_BASE(abA, bA); CALC_BASE(abB, bB); CALC_BASE(abC, bC);

    if (tid < NR) {   // waves 0,1 fully active: linear lane->LDS dest preserved
        GLOAD_LDS16(fd + (size_t)(wbeg + 0) * FSTRIDE + (FOFFS + (int)bA + tid), &buf[0][tid]);
        GLOAD_LDS16(fd + (size_t)(wbeg + 1) * FSTRIDE + (FOFFS + (int)bB + tid), &buf[1][tid]);
        GLOAD_LDS16(fd + (size_t)(wbeg + 2) * FSTRIDE + (FOFFS + (int)bC + tid), &buf[2][tid]);
    }
    asm volatile("s_waitcnt vmcnt(2)" ::: "memory");   // DMA(0) retired
    __builtin_amdgcn_s_barrier();
    __builtin_amdgcn_sched_barrier(0);

    for (int k = 0; k < ANG_PER; ++k) {
        {   // issue DMA for angle k+3 (tail: redirect to valid, never-read window)
            bool ok  = (k + 3 < ANG_PER);
            int  idx = ok ? (k + 3) : 0;
            abD = tl[idx];
            if (ok) { CALC_BASE(abD, bD); } else { bD = 0.0f; }
            int wsrc = ok ? (wbeg + k + 3) : wbeg;
            if (tid < NR)
                GLOAD_LDS16(fd + (size_t)wsrc * FSTRIDE + (FOFFS + (int)bD + tid),
                            &buf[(k + 3) & 3][tid]);
        }

        // compute angle k from buf[k&3]
        float pybase = fmaf(abA.x, jf, 255.5f);
        const float4* cb = buf[k & 3];
#pragma unroll
        for (int u = 0; u < 4; ++u) {
            float pya = fmaf(abA.y, ifl[u], pybase);   // absolute py
            float pyr = pya - bA;                      // exact fp32 sub; in [2, 71)
            float cf  = truncf(pyr);
            float fy  = pyr - cf;
            int   c   = (int)cf;
            float4 p0 = cb[c];
            float4 p1 = cb[c + 1];
            float w0  = 1.f - fy;
            acc[u][0] = fmaf(p1.x, fy, fmaf(p0.x, w0, acc[u][0]));
            acc[u][1] = fmaf(p1.y, fy, fmaf(p0.y, w0, acc[u][1]));
            acc[u][2] = fmaf(p1.z, fy, fmaf(p0.z, w0, acc[u][2]));
            acc[u][3] = fmaf(p1.w, fy, fmaf(p0.w, w0, acc[u][3]));
        }

        asm volatile("s_waitcnt vmcnt(2)" ::: "memory");  // retire oldest
        __builtin_amdgcn_s_barrier();
        __builtin_amdgcn_sched_barrier(0);

        abA = abB; abB = abC; abC = abD;
        bA  = bB;  bB  = bC;  bC  = bD;
    }

    asm volatile("s_waitcnt vmcnt(0)" ::: "memory");   // drain tail DMAs

    // parts layout: [chunk][i*512+j] float4 over n -> 1KB/wave coalesced stores
    float4* p4 = (float4*)parts + (size_t)chunk * PIX;
#pragma unroll
    for (int u = 0; u < 4; ++u)
        p4[(size_t)(i0 + 4 * u) * DD + j] =
            make_float4(acc[u][0], acc[u][1], acc[u][2], acc[u][3]);
#undef CALC_BASE
}

// ---------------- K3: reduce 6 chunks + scale + de-interleave n ----------------
__global__ __launch_bounds__(256) void k_reduce(float* __restrict__ out,
                                                const float* __restrict__ ws) {
    int t = blockIdx.x * 256 + threadIdx.x;            // 262144 pixels
    const float4* p = (const float4*)(ws + OFF_PART);
    float4 a = p[t];
#pragma unroll
    for (int c = 1; c < NCHUNK; ++c) {
        float4 b = p[(size_t)c * PIX + t];
        a.x += b.x; a.y += b.y; a.z += b.z; a.w += b.w;
    }
    const float s = (float)(3.14159265358979323846 / 720.0);
    out[t]           = a.x * s;
    out[PIX + t]     = a.y * s;
    out[2 * PIX + t] = a.z * s;
    out[3 * PIX + t] = a.w * s;
}

extern "C" void kernel_launch(void* const* d_in, const int* in_sizes, int n_in,
                              void* d_out, int out_size, void* d_ws, size_t ws_size,
                              hipStream_t stream) {
    const float* radon = (const float*)d_in[0];
    const float* hG    = (const float*)d_in[1];
    // d_in[2] (t_y, 377MB) intentionally unused: recomputed analytically.
    float* out = (float*)d_out;
    float* ws  = (float*)d_ws;

    k_filter<<<WW, 256, 0, stream>>>(radon, hG, ws);
    k_backproj<<<dim3(8, 32, NCHUNK), 256, 0, stream>>>(ws, ws + OFF_PART);
    k_reduce<<<1024, 256, 0, stream>>>(out, ws);
}